// Round 1
// baseline (157.801 us; speedup 1.0000x reference)
//
#include <hip/hip_runtime.h>
#include <hip/hip_bf16.h>

#define N_NODES 256
#define BATCH   1024

typedef __attribute__((ext_vector_type(8))) short bf16x8;
typedef __attribute__((ext_vector_type(4))) float f32x4;

__device__ __forceinline__ float ftanh(float x) {
    // tanh(x) = 1 - 2/(exp(2x)+1); saturates correctly for |x| large
    float e = __expf(2.0f * x);
    return 1.0f - __fdividef(2.0f, e + 1.0f);
}

__device__ __forceinline__ unsigned short f2bf(float f) {
    unsigned u = __float_as_uint(f);
    return (unsigned short)((u + 0x7fffu + ((u >> 16) & 1u)) >> 16);
}

__device__ __forceinline__ unsigned int pack_bf2(float a, float b) {
    return (unsigned)f2bf(a) | ((unsigned)f2bf(b) << 16);
}

__device__ __forceinline__ float bf2f(short s) {
    return __uint_as_float(((unsigned)(unsigned short)s) << 16);
}

// Swizzled byte offset in a [64][256] bf16 LDS tile (row stride 512 B).
// 16B chunk index XOR'd with row&31 -> conflict-free ds_read_b128 down rows.
__device__ __forceinline__ int swz(int row, int col) {
    int chunk = col >> 3;
    return row * 512 + (((chunk ^ (row & 31)) << 4) | ((col & 7) << 1));
}

// ---------------- P1: Z0 = x @ W0^T, exact fp32 ----------------
__global__ void z0_gemm(const float* __restrict__ x, const float* __restrict__ W0,
                        float* __restrict__ Z0) {
    __shared__ float xs[32][36];
    __shared__ float ws[32][36];
    int t = threadIdx.x;
    int b0 = blockIdx.x * 32, m0 = blockIdx.y * 32;
    int lr = t >> 3, lc = (t & 7) << 2;
    int tr = (t >> 4) << 1, tc = (t & 15) << 1;
    float acc00 = 0.f, acc01 = 0.f, acc10 = 0.f, acc11 = 0.f;
    for (int k0 = 0; k0 < 256; k0 += 32) {
        *(float4*)&xs[lr][lc] = *(const float4*)&x[(b0 + lr) * 256 + k0 + lc];
        *(float4*)&ws[lr][lc] = *(const float4*)&W0[(m0 + lr) * 256 + k0 + lc];
        __syncthreads();
#pragma unroll
        for (int k = 0; k < 32; ++k) {
            float a0 = xs[tr][k], a1 = xs[tr + 1][k];
            float w0v = ws[tc][k], w1v = ws[tc + 1][k];
            acc00 = fmaf(a0, w0v, acc00);
            acc01 = fmaf(a0, w1v, acc01);
            acc10 = fmaf(a1, w0v, acc10);
            acc11 = fmaf(a1, w1v, acc11);
        }
        __syncthreads();
    }
    Z0[(b0 + tr) * 256 + m0 + tc]         = acc00;
    Z0[(b0 + tr) * 256 + m0 + tc + 1]     = acc01;
    Z0[(b0 + tr + 1) * 256 + m0 + tc]     = acc10;
    Z0[(b0 + tr + 1) * 256 + m0 + tc + 1] = acc11;
}

// ---------------- P2: transposes + bf16 conversion ----------------
__global__ void prep(const float* __restrict__ x, const float* __restrict__ W0,
                     const float* __restrict__ W1, float* __restrict__ xT,
                     float* __restrict__ W0col, unsigned short* __restrict__ W1bf) {
    int id = blockIdx.x * 256 + threadIdx.x;   // grid covers 256*1024
    {
        int i = id >> 10, b = id & 1023;
        xT[id] = x[b * 256 + i];
    }
    if (id < 256 * 256) {
        int i = id >> 8, m = id & 255;
        W0col[id] = W0[m * 256 + i];
        W1bf[id] = f2bf(W1[id]);
    }
}

// ---------------- F: fused per-(node i, batch-tile) kernel ----------------
__launch_bounds__(256, 2)
__global__ void fused(const float* __restrict__ Z0, const float* __restrict__ xT,
                      const float* __restrict__ W0col,
                      const unsigned short* __restrict__ W1bf,
                      const float* __restrict__ W2, float* __restrict__ out) {
    __shared__ __align__(16) unsigned char h0s[64 * 512];
    __shared__ __align__(16) unsigned char h1s[64 * 512];
    int t  = threadIdx.x;
    int r0 = blockIdx.x * 64;   // batch tile base
    int i  = blockIdx.y;        // node index

    // ---- phase 0: h0 = tanh(Z0 - x[:,i] (x) W0[:,i]) -> LDS (bf16, swizzled)
    {
        int rowgrp = t >> 5, chunk = t & 31;
        int col0 = chunk << 3;
        float4 w0a = *(const float4*)&W0col[i * 256 + col0];
        float4 w0b = *(const float4*)&W0col[i * 256 + col0 + 4];
        float w[8] = {w0a.x, w0a.y, w0a.z, w0a.w, w0b.x, w0b.y, w0b.z, w0b.w};
#pragma unroll
        for (int p = 0; p < 8; ++p) {
            int row = p * 8 + rowgrp;
            float xi = xT[i * 1024 + r0 + row];
            float4 za = *(const float4*)&Z0[(r0 + row) * 256 + col0];
            float4 zb = *(const float4*)&Z0[(r0 + row) * 256 + col0 + 4];
            float z[8] = {za.x, za.y, za.z, za.w, zb.x, zb.y, zb.z, zb.w};
            unsigned pk[4];
#pragma unroll
            for (int e = 0; e < 4; ++e) {
                float ha = ftanh(z[2 * e]     - xi * w[2 * e]);
                float hb = ftanh(z[2 * e + 1] - xi * w[2 * e + 1]);
                pk[e] = pack_bf2(ha, hb);
            }
            uint4 v = make_uint4(pk[0], pk[1], pk[2], pk[3]);
            *(uint4*)(h0s + row * 512 + (((chunk ^ (row & 31)) << 4))) = v;
        }
    }
    __syncthreads();

    // ---- phase 1: z1 = h0 @ W1^T via MFMA; h1 = tanh(z1) -> LDS
    int wave = t >> 6, lane = t & 63;
    int lr = lane & 15, lh = lane >> 4;
    f32x4 acc[4][4];
#pragma unroll
    for (int a = 0; a < 4; ++a)
#pragma unroll
        for (int b = 0; b < 4; ++b)
            acc[a][b] = (f32x4){0.f, 0.f, 0.f, 0.f};

#pragma unroll
    for (int ks = 0; ks < 8; ++ks) {
        int kk = ks * 32 + lh * 8;
        int chunk = kk >> 3;
        bf16x8 afrag[4], bfrag[4];
#pragma unroll
        for (int mt = 0; mt < 4; ++mt) {
            int row = mt * 16 + lr;
            afrag[mt] = *(const bf16x8*)(h0s + row * 512 + ((chunk ^ (row & 31)) << 4));
        }
#pragma unroll
        for (int nt = 0; nt < 4; ++nt) {
            int j = wave * 64 + nt * 16 + lr;   // output-feature row of W1
            bfrag[nt] = *(const bf16x8*)(W1bf + j * 256 + kk);
        }
#pragma unroll
        for (int mt = 0; mt < 4; ++mt)
#pragma unroll
            for (int nt = 0; nt < 4; ++nt)
                acc[mt][nt] = __builtin_amdgcn_mfma_f32_16x16x32_bf16(
                    afrag[mt], bfrag[nt], acc[mt][nt], 0, 0, 0);
    }

#pragma unroll
    for (int mt = 0; mt < 4; ++mt) {
#pragma unroll
        for (int nt = 0; nt < 4; ++nt) {
#pragma unroll
            for (int r = 0; r < 4; ++r) {
                int row = mt * 16 + lh * 4 + r;          // C/D: row=(lane>>4)*4+reg
                int col = wave * 64 + nt * 16 + lr;      //      col=lane&15
                float h = ftanh(acc[mt][nt][r]);
                *(unsigned short*)(h1s + swz(row, col)) = f2bf(h);
            }
        }
    }
    __syncthreads();

    // ---- phase 2: f[b,i] = tanh( h1[b,:] . W2[i,:] )
    {
        int b = t >> 2, part = t & 3;
        float sum = 0.f;
#pragma unroll
        for (int c8 = 0; c8 < 8; ++c8) {
            int chunk = part * 8 + c8;
            bf16x8 hv = *(const bf16x8*)(h1s + b * 512 + ((chunk ^ (b & 31)) << 4));
            float4 wa = *(const float4*)&W2[i * 256 + chunk * 8];
            float4 wb = *(const float4*)&W2[i * 256 + chunk * 8 + 4];
            const float* wap = (const float*)&wa;
            const float* wbp = (const float*)&wb;
#pragma unroll
            for (int e = 0; e < 4; ++e) {
                sum = fmaf(bf2f(hv[e]),     wap[e], sum);
                sum = fmaf(bf2f(hv[e + 4]), wbp[e], sum);
            }
        }
        sum += __shfl_xor(sum, 1);
        sum += __shfl_xor(sum, 2);
        if (part == 0) out[(r0 + b) * 256 + i] = ftanh(sum);
    }
}

extern "C" void kernel_launch(void* const* d_in, const int* in_sizes, int n_in,
                              void* d_out, int out_size, void* d_ws, size_t ws_size,
                              hipStream_t stream) {
    const float* x  = (const float*)d_in[0];
    const float* W0 = (const float*)d_in[1];
    const float* W1 = (const float*)d_in[2];
    const float* W2 = (const float*)d_in[3];
    float* out = (float*)d_out;

    char* ws = (char*)d_ws;
    float* Z0            = (float*)ws;                               // 1 MB
    float* xT            = (float*)(ws + (1 << 20));                 // 1 MB
    float* W0col         = (float*)(ws + (2 << 20));                 // 256 KB
    unsigned short* W1bf = (unsigned short*)(ws + (2 << 20) + (256 << 10)); // 128 KB

    z0_gemm<<<dim3(32, 8), 256, 0, stream>>>(x, W0, Z0);
    prep<<<dim3(1024), 256, 0, stream>>>(x, W0, W1, xT, W0col, W1bf);
    fused<<<dim3(16, 256), 256, 0, stream>>>(Z0, xT, W0col, W1bf, W2, out);
}

// Round 2
// 88.362 us; speedup vs baseline: 1.7858x; 1.7858x over previous
//
#include <hip/hip_runtime.h>
#include <hip/hip_bf16.h>

#define N_NODES 256
#define BATCH   1024

typedef __attribute__((ext_vector_type(8))) short bf16x8;
typedef __attribute__((ext_vector_type(4))) float f32x4;

__device__ __forceinline__ float ftanh(float x) {
    // tanh(x) = 1 - 2/(exp2(x*2*log2e)+1); exp2+rcp saturate correctly
    float e = __builtin_amdgcn_exp2f(x * 2.8853900817779268f);
    float r = __builtin_amdgcn_rcpf(e + 1.0f);
    return fmaf(-2.0f, r, 1.0f);
}

__device__ __forceinline__ unsigned short f2bf(float f) {
    unsigned u = __float_as_uint(f);
    return (unsigned short)((u + 0x7fffu + ((u >> 16) & 1u)) >> 16);
}

__device__ __forceinline__ unsigned pack_bf2(float a, float b) {
    union { __hip_bfloat162 h; unsigned u; } cvt;
    cvt.h = __float22bfloat162_rn(make_float2(a, b));
    return cvt.u;
}

// ---------------- P1: Z0 = x @ W0^T, exact fp32 ----------------
__global__ void z0_gemm(const float* __restrict__ x, const float* __restrict__ W0,
                        float* __restrict__ Z0) {
    __shared__ float xs[32][36];
    __shared__ float ws[32][36];
    int t = threadIdx.x;
    int b0 = blockIdx.x * 32, m0 = blockIdx.y * 32;
    int lr = t >> 3, lc = (t & 7) << 2;
    int tr = (t >> 4) << 1, tc = (t & 15) << 1;
    float acc00 = 0.f, acc01 = 0.f, acc10 = 0.f, acc11 = 0.f;
    for (int k0 = 0; k0 < 256; k0 += 32) {
        *(float4*)&xs[lr][lc] = *(const float4*)&x[(b0 + lr) * 256 + k0 + lc];
        *(float4*)&ws[lr][lc] = *(const float4*)&W0[(m0 + lr) * 256 + k0 + lc];
        __syncthreads();
#pragma unroll
        for (int k = 0; k < 32; ++k) {
            float a0 = xs[tr][k], a1 = xs[tr + 1][k];
            float w0v = ws[tc][k], w1v = ws[tc + 1][k];
            acc00 = fmaf(a0, w0v, acc00);
            acc01 = fmaf(a0, w1v, acc01);
            acc10 = fmaf(a1, w0v, acc10);
            acc11 = fmaf(a1, w1v, acc11);
        }
        __syncthreads();
    }
    Z0[(b0 + tr) * 256 + m0 + tc]         = acc00;
    Z0[(b0 + tr) * 256 + m0 + tc + 1]     = acc01;
    Z0[(b0 + tr + 1) * 256 + m0 + tc]     = acc10;
    Z0[(b0 + tr + 1) * 256 + m0 + tc + 1] = acc11;
}

// ---------------- P2: transposes + bf16 conversion ----------------
__global__ void prep(const float* __restrict__ x, const float* __restrict__ W0,
                     const float* __restrict__ W1, float* __restrict__ xT,
                     float* __restrict__ W0col, unsigned short* __restrict__ W1bf) {
    int id = blockIdx.x * 256 + threadIdx.x;   // grid covers 256*1024
    {
        int i = id >> 10, b = id & 1023;
        xT[id] = x[b * 256 + i];
    }
    if (id < 256 * 256) {
        int i = id >> 8, m = id & 255;
        W0col[id] = W0[m * 256 + i];
        W1bf[id] = f2bf(W1[id]);
    }
}

// ---------------- F: fused per-(node i, batch-tile) kernel ----------------
__launch_bounds__(256, 4)
__global__ void fused(const float* __restrict__ Z0, const float* __restrict__ xT,
                      const float* __restrict__ W0col,
                      const unsigned short* __restrict__ W1bf,
                      const float* __restrict__ W2, float* __restrict__ out) {
    __shared__ __align__(16) unsigned char h0s[64 * 512];   // 32 KiB
    __shared__ float wavepart[4][64];                        // 1 KiB
    int t  = threadIdx.x;
    int r0 = blockIdx.x * 64;   // batch tile base
    int i  = blockIdx.y;        // node index

    int wave = t >> 6, lane = t & 63;
    int lr = lane & 15, lh = lane >> 4;

    // W2 values for this lane's output columns (hide latency under phase 0)
    float w2v[4];
#pragma unroll
    for (int nt = 0; nt < 4; ++nt)
        w2v[nt] = W2[i * 256 + wave * 64 + nt * 16 + lr];

    // ---- phase 0: h0 = tanh(Z0 - x[:,i] (x) W0[:,i]) -> LDS (bf16, swizzled)
    {
        int rowgrp = t >> 5, chunk = t & 31;
        int col0 = chunk << 3;
        float4 w0a = *(const float4*)&W0col[i * 256 + col0];
        float4 w0b = *(const float4*)&W0col[i * 256 + col0 + 4];
        float w[8] = {w0a.x, w0a.y, w0a.z, w0a.w, w0b.x, w0b.y, w0b.z, w0b.w};
#pragma unroll
        for (int p = 0; p < 8; ++p) {
            int row = p * 8 + rowgrp;
            float xi = xT[i * 1024 + r0 + row];
            float4 za = *(const float4*)&Z0[(r0 + row) * 256 + col0];
            float4 zb = *(const float4*)&Z0[(r0 + row) * 256 + col0 + 4];
            float z[8] = {za.x, za.y, za.z, za.w, zb.x, zb.y, zb.z, zb.w};
            unsigned pk[4];
#pragma unroll
            for (int e = 0; e < 4; ++e) {
                float ha = ftanh(fmaf(-xi, w[2 * e],     z[2 * e]));
                float hb = ftanh(fmaf(-xi, w[2 * e + 1], z[2 * e + 1]));
                pk[e] = pack_bf2(ha, hb);
            }
            uint4 v = make_uint4(pk[0], pk[1], pk[2], pk[3]);
            *(uint4*)(h0s + row * 512 + (((chunk ^ (row & 31)) << 4))) = v;
        }
    }
    __syncthreads();

    // ---- phase 1: z1 = h0 @ W1^T via MFMA
    f32x4 acc[4][4];
#pragma unroll
    for (int a = 0; a < 4; ++a)
#pragma unroll
        for (int b = 0; b < 4; ++b)
            acc[a][b] = (f32x4){0.f, 0.f, 0.f, 0.f};

#pragma unroll
    for (int ks = 0; ks < 8; ++ks) {
        int kk = ks * 32 + lh * 8;
        int chunk = kk >> 3;
        bf16x8 afrag[4], bfrag[4];
#pragma unroll
        for (int mt = 0; mt < 4; ++mt) {
            int row = mt * 16 + lr;
            afrag[mt] = *(const bf16x8*)(h0s + row * 512 + ((chunk ^ (row & 31)) << 4));
        }
#pragma unroll
        for (int nt = 0; nt < 4; ++nt) {
            int j = wave * 64 + nt * 16 + lr;   // output-feature row of W1
            bfrag[nt] = *(const bf16x8*)(W1bf + j * 256 + kk);
        }
#pragma unroll
        for (int mt = 0; mt < 4; ++mt)
#pragma unroll
            for (int nt = 0; nt < 4; ++nt)
                acc[mt][nt] = __builtin_amdgcn_mfma_f32_16x16x32_bf16(
                    afrag[mt], bfrag[nt], acc[mt][nt], 0, 0, 0);
    }

    // ---- phase 2 (in-register): h1 = tanh(z1); partial dot with W2 row i;
    //      butterfly-reduce over the 16-lane lr group; combine waves via LDS.
    //      C/D: row = mt*16 + lh*4 + r, col = wave*64 + nt*16 + lr
    float part[4][4];
#pragma unroll
    for (int mt = 0; mt < 4; ++mt) {
#pragma unroll
        for (int r = 0; r < 4; ++r) {
            float s = 0.f;
#pragma unroll
            for (int nt = 0; nt < 4; ++nt)
                s = fmaf(ftanh(acc[mt][nt][r]), w2v[nt], s);
            // reduce across lr (lane bits 0..3); lh bits untouched
            s += __shfl_xor(s, 1);
            s += __shfl_xor(s, 2);
            s += __shfl_xor(s, 4);
            s += __shfl_xor(s, 8);
            part[mt][r] = s;
        }
    }
    if (lr == 0) {
#pragma unroll
        for (int mt = 0; mt < 4; ++mt)
#pragma unroll
            for (int r = 0; r < 4; ++r)
                wavepart[wave][mt * 16 + lh * 4 + r] = part[mt][r];
    }
    __syncthreads();

    // ---- phase 3: sum 4 wave partials, final tanh, store column i
    if (t < 64) {
        float s = wavepart[0][t] + wavepart[1][t] + wavepart[2][t] + wavepart[3][t];
        out[(r0 + t) * 256 + i] = ftanh(s);
    }
}

extern "C" void kernel_launch(void* const* d_in, const int* in_sizes, int n_in,
                              void* d_out, int out_size, void* d_ws, size_t ws_size,
                              hipStream_t stream) {
    const float* x  = (const float*)d_in[0];
    const float* W0 = (const float*)d_in[1];
    const float* W1 = (const float*)d_in[2];
    const float* W2 = (const float*)d_in[3];
    float* out = (float*)d_out;

    char* ws = (char*)d_ws;
    float* Z0            = (float*)ws;                               // 1 MB
    float* xT            = (float*)(ws + (1 << 20));                 // 1 MB
    float* W0col         = (float*)(ws + (2 << 20));                 // 256 KB
    unsigned short* W1bf = (unsigned short*)(ws + (2 << 20) + (256 << 10)); // 128 KB

    z0_gemm<<<dim3(32, 8), 256, 0, stream>>>(x, W0, Z0);
    prep<<<dim3(1024), 256, 0, stream>>>(x, W0, W1, xT, W0col, W1bf);
    fused<<<dim3(16, 256), 256, 0, stream>>>(Z0, xT, W0col, W1bf, W2, out);
}